// Round 5
// baseline (190.456 us; speedup 1.0000x reference)
//
#include <hip/hip_runtime.h>
#include <hip/hip_bf16.h>
#include <stdint.h>

#define N_MODELS 16
#define IN_F 1024
#define OUT_F 1024
#define N_TOK 8192
#define MAX_MT 80          // max m-tiles: 64 full + up to 15 fragmentation

typedef unsigned short u16;
using us4   = __attribute__((ext_vector_type(4))) unsigned short;
using s16x8 = __attribute__((ext_vector_type(8))) short;
using f32x4 = __attribute__((ext_vector_type(4))) float;

__device__ __forceinline__ u16 f2bf(float f) {
    union { float f; uint32_t u; } v;
    v.f = f;
    uint32_t u = v.u;
    u += 0x7fffu + ((u >> 16) & 1u);   // RNE
    return (u16)(u >> 16);
}

__device__ __forceinline__ void gload16(const u16* g, u16* l) {
    // async global->LDS DMA, 16 B/lane; LDS dest = wave-uniform base + lane*16
    __builtin_amdgcn_global_load_lds(
        (const __attribute__((address_space(1))) void*)g,
        (__attribute__((address_space(3))) void*)l, 16, 0, 0);
}

// ---------------- kernel 1: prep (w-transpose, ILP-unrolled) + setup (block WBLOCKS) ----------------
// wT layout (u16): ((((e*8 + nt)*32 + kb)*4 + q)*128 + n)*8 + j
#define WBLOCKS (16 * 8 * 16)   // 2048 (e, nt, 64-k group)
#define ROW 17                  // LDS row stride (ints) for [256][16] tables

__global__ __launch_bounds__(256)
void prep_kernel(const float* __restrict__ w, const int* __restrict__ idxs,
                 u16* __restrict__ wT,
                 int* __restrict__ perm, int* __restrict__ offs,
                 int* __restrict__ tile_off)
{
    __shared__ int shmem[256 * ROW + N_MODELS + 1];
    int t  = threadIdx.x;
    int bx = blockIdx.x;

    if (bx < WBLOCKS) {
        // ---- w fp32 [k][n] -> wT bf16 frag-major; 32 loads in flight ----
        int e   = bx >> 7;
        int nt  = (bx >> 4) & 7;
        int kb2 = bx & 15;           // 64-k group
        int n    = t & 127;
        int half = t >> 7;           // 0..1
        const float* wp = w + (size_t)e * (IN_F * OUT_F) + (size_t)kb2 * 64 * OUT_F + nt * 128 + n;
        u16* ob = wT + ((size_t)(e * 8 + nt) * 32 + kb2 * 2) * 4096;
        float r[32];
#pragma unroll
        for (int i = 0; i < 4; ++i) {
            int ko = half + i * 2;   // k-octet within 64-k group
#pragma unroll
            for (int j = 0; j < 8; ++j)
                r[i * 8 + j] = wp[(size_t)(ko * 8 + j) * OUT_F];
        }
#pragma unroll
        for (int i = 0; i < 4; ++i) {
            int ko = half + i * 2;
            s16x8 v;
#pragma unroll
            for (int j = 0; j < 8; ++j) v[j] = (short)f2bf(r[i * 8 + j]);
            *(s16x8*)(ob + ((size_t)((ko >> 2) * 4 + (ko & 3)) * 128 + n) * 8) = v;
        }
    } else {
        // ---- setup: hist + Hillis-Steele scan + deterministic rank scatter ----
        int* cnt   = shmem;
        int* offsS = shmem + 256 * ROW;
#pragma unroll
        for (int e = 0; e < N_MODELS; ++e) cnt[t * ROW + e] = 0;
        __syncthreads();
        int base = t * 32;
#pragma unroll
        for (int i = 0; i < 32; ++i) cnt[t * ROW + idxs[base + i]] += 1;
        __syncthreads();
#pragma unroll
        for (int s = 1; s < 256; s <<= 1) {
            int v[N_MODELS];
#pragma unroll
            for (int e = 0; e < N_MODELS; ++e)
                v[e] = (t >= s) ? cnt[(t - s) * ROW + e] : 0;
            __syncthreads();
#pragma unroll
            for (int e = 0; e < N_MODELS; ++e)
                cnt[t * ROW + e] += v[e];
            __syncthreads();
        }
        if (t == 0) {
            int o = 0, to = 0;
            for (int e = 0; e < N_MODELS; ++e) {
                int c = cnt[255 * ROW + e];
                offsS[e] = o;
                offs[e] = o; tile_off[e] = to;
                to += (c + 127) >> 7;
                o  += c;
            }
            offsS[N_MODELS] = o;
            offs[N_MODELS] = o; tile_off[N_MODELS] = to;
        }
        __syncthreads();
        int cur[N_MODELS];
#pragma unroll
        for (int e = 0; e < N_MODELS; ++e)
            cur[e] = offsS[e] + ((t > 0) ? cnt[(t - 1) * ROW + e] : 0);
        __syncthreads();
#pragma unroll
        for (int e = 0; e < N_MODELS; ++e) cnt[t * ROW + e] = cur[e];
#pragma unroll
        for (int i = 0; i < 32; ++i) {
            int tok = base + i;
            int e = idxs[tok];
            perm[cnt[t * ROW + e]++] = tok;
        }
    }
}

// ---------------- kernel 2: grouped GEMM, fused A fp32->bf16, B via DMA ----------------
__global__ __launch_bounds__(256)
void gemm_kernel(const float* __restrict__ x, const u16* __restrict__ wT,
                 const float* __restrict__ bias,
                 const int* __restrict__ perm, const int* __restrict__ offs,
                 const int* __restrict__ tile_off,
                 float* __restrict__ out)
{
    __shared__ u16 As[4096];
    __shared__ u16 Bs[4096];
    __shared__ int   permS[128];
    __shared__ float biasS[128];
    __shared__ int   toS[N_MODELS + 1];

    int t  = threadIdx.x;
    int bt = blockIdx.y;            // flat m-tile id
    int nt = blockIdx.x;            // n-tile id

    if (t <= N_MODELS) toS[t] = tile_off[t];
    __syncthreads();
    if (bt >= toS[N_MODELS]) return;   // uniform

    int e = 0;
    while (toS[e + 1] <= bt) ++e;
    int s0   = offs[e] + (bt - toS[e]) * 128;
    int sEnd = offs[e + 1];
    int mValid = sEnd - s0; if (mValid > 128) mValid = 128;

    if (t < 128) {
        permS[t] = (s0 + t < sEnd) ? perm[s0 + t] : 0;
        biasS[t] = bias[(size_t)e * OUT_F + nt * 128 + t];
    }
    __syncthreads();

    // A staging precompute: thread owns 4 16B-chunks of the 128x32 A tile
    const float* px[4];
    int la[4];
#pragma unroll
    for (int i = 0; i < 4; ++i) {
        int c    = t + i * 256;      // chunk id 0..1023
        int r    = c >> 3;           // row in tile
        int apos = c & 7;            // 16B chunk within 32-k window
        px[i] = x + (size_t)permS[r] * IN_F + apos * 4;
        la[i] = (apos >> 1) * 1024 + r * 8 + (apos & 1) * 4;   // frag-major u16 index
    }

    const u16* btile = wT + ((size_t)(e * 8 + nt) * 32) * 4096;

    int lane = t & 63;
    int wv   = t >> 6;
    int wm   = (wv >> 1) * 64;
    int wn   = (wv & 1) * 64;
    int m    = lane & 15;
    int q    = lane >> 4;

    f32x4 acc[4][4];
#pragma unroll
    for (int i = 0; i < 4; ++i)
#pragma unroll
        for (int j = 0; j < 4; ++j)
            acc[i][j] = (f32x4){0.f, 0.f, 0.f, 0.f};

    int c2 = wv * 2;   // this wave's 1 KB chunk base in Bs

    for (int kb = 0; kb < 32; ++kb) {
        // B: DMA bf16 tile
        const u16* gb = btile + kb * 4096;
        gload16(gb + (c2    ) * 512 + lane * 8, &Bs[(c2    ) * 512]);
        gload16(gb + (c2 + 1) * 512 + lane * 8, &Bs[(c2 + 1) * 512]);
        // A: fp32 load + packed convert + LDS write (frag-major)
#pragma unroll
        for (int i = 0; i < 4; ++i) {
            const float4 v = *(const float4*)(px[i] + kb * 32);
            union { __hip_bfloat162 h; uint32_t u; } lo, hi;
            lo.h = __float22bfloat162_rn(make_float2(v.x, v.y));
            hi.h = __float22bfloat162_rn(make_float2(v.z, v.w));
            union { us4 s; uint32_t u[2]; } pk;
            pk.u[0] = lo.u; pk.u[1] = hi.u;
            *(us4*)(&As[la[i]]) = pk.s;
        }
        __syncthreads();

        s16x8 af[4], bf[4];
#pragma unroll
        for (int mt2 = 0; mt2 < 4; ++mt2)
            af[mt2] = *(const s16x8*)(&As[q * 1024 + (wm + mt2 * 16 + m) * 8]);
#pragma unroll
        for (int nt2 = 0; nt2 < 4; ++nt2)
            bf[nt2] = *(const s16x8*)(&Bs[q * 1024 + (wn + nt2 * 16 + m) * 8]);
#pragma unroll
        for (int mt2 = 0; mt2 < 4; ++mt2)
#pragma unroll
            for (int nt2 = 0; nt2 < 4; ++nt2)
                acc[mt2][nt2] = __builtin_amdgcn_mfma_f32_16x16x32_bf16(
                    af[mt2], bf[nt2], acc[mt2][nt2], 0, 0, 0);
        __syncthreads();
    }

    // epilogue: bias + relu, scatter rows by perm
#pragma unroll
    for (int mt2 = 0; mt2 < 4; ++mt2) {
        int rbase = wm + mt2 * 16 + q * 4;
#pragma unroll
        for (int i = 0; i < 4; ++i) {
            int r = rbase + i;
            if (r < mValid) {
                int tok = permS[r];
                float* orow = out + (size_t)tok * OUT_F + nt * 128;
#pragma unroll
                for (int nt2 = 0; nt2 < 4; ++nt2) {
                    int col = wn + nt2 * 16 + m;
                    float v = acc[mt2][nt2][i] + biasS[col];
                    orow[col] = v > 0.f ? v : 0.f;
                }
            }
        }
    }
}

extern "C" void kernel_launch(void* const* d_in, const int* in_sizes, int n_in,
                              void* d_out, int out_size, void* d_ws, size_t ws_size,
                              hipStream_t stream) {
    const float* x    = (const float*)d_in[0];
    const int*   idxs = (const int*)d_in[1];
    const float* w    = (const float*)d_in[2];
    const float* b    = (const float*)d_in[3];
    float* out = (float*)d_out;

    // ws layout: wT u16[16M] (32 MB) | perm [8192] | offs [17] | tile_off [17]
    u16* wT = (u16*)d_ws;
    int* perm     = (int*)(wT + (size_t)N_MODELS * IN_F * OUT_F);
    int* offs     = perm + N_TOK;
    int* tile_off = offs + (N_MODELS + 1);

    prep_kernel<<<WBLOCKS + 1, 256, 0, stream>>>(w, idxs, wT, perm, offs, tile_off);
    gemm_kernel<<<dim3(8, MAX_MT), 256, 0, stream>>>(x, wT, b, perm, offs, tile_off, out);
}

// Round 6
// 185.044 us; speedup vs baseline: 1.0292x; 1.0292x over previous
//
#include <hip/hip_runtime.h>
#include <hip/hip_bf16.h>
#include <stdint.h>

#define N_MODELS 16
#define IN_F 1024
#define OUT_F 1024
#define N_TOK 8192
#define MAX_MT 80          // max m-tiles: 64 full + up to 15 fragmentation

typedef unsigned short u16;
using us4   = __attribute__((ext_vector_type(4))) unsigned short;
using s16x8 = __attribute__((ext_vector_type(8))) short;
using f32x4 = __attribute__((ext_vector_type(4))) float;

__device__ __forceinline__ u16 f2bf(float f) {
    union { float f; uint32_t u; } v;
    v.f = f;
    uint32_t u = v.u;
    u += 0x7fffu + ((u >> 16) & 1u);   // RNE
    return (u16)(u >> 16);
}

__device__ __forceinline__ void gload16(const u16* g, u16* l) {
    // async global->LDS DMA, 16 B/lane; LDS dest = wave-uniform base + lane*16
    __builtin_amdgcn_global_load_lds(
        (const __attribute__((address_space(1))) void*)g,
        (__attribute__((address_space(3))) void*)l, 16, 0, 0);
}

// ---------------- kernel 1: setup — hist + scan + deterministic rank scatter ----------------
#define ROW 17   // LDS row stride (ints) for [256][16] tables -> conflict-free
__global__ __launch_bounds__(256)
void setup_kernel(const int* __restrict__ idxs,
                  int* __restrict__ perm,
                  int* __restrict__ offs,       // [17]
                  int* __restrict__ tile_off)   // [17]
{
    __shared__ int cnt[256 * ROW];
    __shared__ int offsS[N_MODELS + 1];
    int t = threadIdx.x;

#pragma unroll
    for (int e = 0; e < N_MODELS; ++e) cnt[t * ROW + e] = 0;
    __syncthreads();

    int base = t * 32;
#pragma unroll
    for (int i = 0; i < 32; ++i) cnt[t * ROW + idxs[base + i]] += 1;
    __syncthreads();

#pragma unroll
    for (int s = 1; s < 256; s <<= 1) {
        int v[N_MODELS];
#pragma unroll
        for (int e = 0; e < N_MODELS; ++e)
            v[e] = (t >= s) ? cnt[(t - s) * ROW + e] : 0;
        __syncthreads();
#pragma unroll
        for (int e = 0; e < N_MODELS; ++e)
            cnt[t * ROW + e] += v[e];
        __syncthreads();
    }

    if (t == 0) {
        int o = 0, to = 0;
        for (int e = 0; e < N_MODELS; ++e) {
            int c = cnt[255 * ROW + e];
            offsS[e] = o;
            offs[e] = o; tile_off[e] = to;
            to += (c + 127) >> 7;
            o  += c;
        }
        offsS[N_MODELS] = o;
        offs[N_MODELS] = o; tile_off[N_MODELS] = to;
    }
    __syncthreads();

    int cur[N_MODELS];
#pragma unroll
    for (int e = 0; e < N_MODELS; ++e)
        cur[e] = offsS[e] + ((t > 0) ? cnt[(t - 1) * ROW + e] : 0);
    __syncthreads();
#pragma unroll
    for (int e = 0; e < N_MODELS; ++e) cnt[t * ROW + e] = cur[e];

#pragma unroll
    for (int i = 0; i < 32; ++i) {
        int tok = base + i;
        int e = idxs[tok];
        perm[cnt[t * ROW + e]++] = tok;
    }
}

// ---------------- kernel 2: prep — ILP w-transpose + x-gather to frag-major bf16 ----------------
// wT layout (u16): ((((e*8 + nt)*32 + kb)*4 + q)*128 + n)*8 + j
// xg layout (u16): mt*131072 + kb*4096 + q*1024 + r*8 + j
#define WBLOCKS (16 * 8 * 16)   // 2048 (e, nt, 64-k group)
#define XBLOCKS (MAX_MT * 8)    // 640  (mt, 128-k group)

__global__ __launch_bounds__(256)
void prep_kernel(const float* __restrict__ w, const float* __restrict__ x,
                 const int* __restrict__ perm, const int* __restrict__ offs,
                 const int* __restrict__ tile_off,
                 u16* __restrict__ wT, u16* __restrict__ xg)
{
    int t  = threadIdx.x;
    int bx = blockIdx.x;

    if (bx < WBLOCKS) {
        // ---- w fp32 [k][n] -> wT bf16 frag-major; 32 column loads in flight ----
        int e   = bx >> 7;
        int nt  = (bx >> 4) & 7;
        int kb2 = bx & 15;           // 64-k group
        int n    = t & 127;
        int half = t >> 7;           // 0..1
        const float* wp = w + (size_t)e * (IN_F * OUT_F) + (size_t)kb2 * 64 * OUT_F + nt * 128 + n;
        u16* ob = wT + ((size_t)(e * 8 + nt) * 32 + kb2 * 2) * 4096;
        float r[32];
#pragma unroll
        for (int i = 0; i < 4; ++i) {
            int ko = half + i * 2;   // k-octet within 64-k group
#pragma unroll
            for (int j = 0; j < 8; ++j)
                r[i * 8 + j] = wp[(size_t)(ko * 8 + j) * OUT_F];
        }
#pragma unroll
        for (int i = 0; i < 4; ++i) {
            int ko = half + i * 2;
            s16x8 v;
#pragma unroll
            for (int j = 0; j < 8; ++j) v[j] = (short)f2bf(r[i * 8 + j]);
            *(s16x8*)(ob + ((size_t)((ko >> 2) * 4 + (ko & 3)) * 128 + n) * 8) = v;
        }
    } else {
        // ---- x fp32 gathered by perm -> xg bf16 frag-major (LDS-staged coalesced stores) ----
        __shared__ u16 sh[4096];
        int bx2 = bx - WBLOCKS;
        int mt  = bx2 >> 3;
        int kg  = bx2 & 7;           // 128-k group
        int total = tile_off[N_MODELS];
        if (mt >= total) return;
        int e = 0;
        while (tile_off[e + 1] <= mt) ++e;
        int s0   = offs[e] + (mt - tile_off[e]) * 128;
        int sEnd = offs[e + 1];
        int r0   = t >> 3;
        int apos = t & 7;
        int toks[4];
#pragma unroll
        for (int i = 0; i < 4; ++i) {
            int r = r0 + i * 32;
            toks[i] = (s0 + r < sEnd) ? perm[s0 + r] : -1;
        }
        u16* outx = xg + (size_t)mt * 32 * 4096;
        for (int kb4 = 0; kb4 < 4; ++kb4) {
            int kb = kg * 4 + kb4;
#pragma unroll
            for (int i = 0; i < 4; ++i) {
                int r = r0 + i * 32;
                int k = kb * 32 + apos * 4;
                float4 v;
                if (toks[i] >= 0) v = *(const float4*)(x + (size_t)toks[i] * IN_F + k);
                else              v = make_float4(0.f, 0.f, 0.f, 0.f);
                us4 pk; pk.x = f2bf(v.x); pk.y = f2bf(v.y); pk.z = f2bf(v.z); pk.w = f2bf(v.w);
                *(us4*)(&sh[(apos >> 1) * 1024 + r * 8 + (apos & 1) * 4]) = pk;
            }
            __syncthreads();
#pragma unroll
            for (int i = 0; i < 2; ++i) {
                int c = t + i * 256;
                *(s16x8*)(outx + (size_t)kb * 4096 + c * 8) = *(const s16x8*)(&sh[c * 8]);
            }
            __syncthreads();
        }
    }
}

// ---------------- kernel 3: grouped GEMM + bias + relu (m97 structure, pure DMA) ----------------
__global__ __launch_bounds__(256)
void gemm_kernel(const u16* __restrict__ xg, const u16* __restrict__ wT,
                 const float* __restrict__ bias,
                 const int* __restrict__ perm, const int* __restrict__ offs,
                 const int* __restrict__ tile_off,
                 float* __restrict__ out)
{
    __shared__ u16 As[4096];
    __shared__ u16 Bs[4096];
    __shared__ int   permS[128];
    __shared__ float biasS[128];
    __shared__ int   toS[N_MODELS + 1];

    int t  = threadIdx.x;
    int bt = blockIdx.y;            // flat m-tile id
    int nt = blockIdx.x;            // n-tile id

    if (t <= N_MODELS) toS[t] = tile_off[t];
    __syncthreads();
    if (bt >= toS[N_MODELS]) return;   // uniform

    int e = 0;
    while (toS[e + 1] <= bt) ++e;
    int s0   = offs[e] + (bt - toS[e]) * 128;
    int sEnd = offs[e + 1];
    int mValid = sEnd - s0; if (mValid > 128) mValid = 128;

    if (t < 128) {
        permS[t] = (s0 + t < sEnd) ? perm[s0 + t] : 0;
        biasS[t] = bias[(size_t)e * OUT_F + nt * 128 + t];
    }

    const u16* atile = xg + (size_t)bt * 32 * 4096;
    const u16* btile = wT + ((size_t)(e * 8 + nt) * 32) * 4096;

    int lane = t & 63;
    int wv   = t >> 6;
    int wm   = (wv >> 1) * 64;
    int wn   = (wv & 1) * 64;
    int m    = lane & 15;
    int q    = lane >> 4;

    f32x4 acc[4][4];
#pragma unroll
    for (int i = 0; i < 4; ++i)
#pragma unroll
        for (int j = 0; j < 4; ++j)
            acc[i][j] = (f32x4){0.f, 0.f, 0.f, 0.f};

    int c = wv * 2;   // this wave's 1 KB chunk base (8 chunks per 8 KB tile)

    for (int kb = 0; kb < 32; ++kb) {
        const u16* ga = atile + kb * 4096;
        const u16* gb = btile + kb * 4096;
        gload16(ga + (c    ) * 512 + lane * 8, &As[(c    ) * 512]);
        gload16(ga + (c + 1) * 512 + lane * 8, &As[(c + 1) * 512]);
        gload16(gb + (c    ) * 512 + lane * 8, &Bs[(c    ) * 512]);
        gload16(gb + (c + 1) * 512 + lane * 8, &Bs[(c + 1) * 512]);
        __syncthreads();

        s16x8 af[4], bf[4];
#pragma unroll
        for (int mt2 = 0; mt2 < 4; ++mt2)
            af[mt2] = *(const s16x8*)(&As[q * 1024 + (wm + mt2 * 16 + m) * 8]);
#pragma unroll
        for (int nt2 = 0; nt2 < 4; ++nt2)
            bf[nt2] = *(const s16x8*)(&Bs[q * 1024 + (wn + nt2 * 16 + m) * 8]);
#pragma unroll
        for (int mt2 = 0; mt2 < 4; ++mt2)
#pragma unroll
            for (int nt2 = 0; nt2 < 4; ++nt2)
                acc[mt2][nt2] = __builtin_amdgcn_mfma_f32_16x16x32_bf16(
                    af[mt2], bf[nt2], acc[mt2][nt2], 0, 0, 0);
        __syncthreads();
    }

    // epilogue: bias + relu, scatter rows by perm
#pragma unroll
    for (int mt2 = 0; mt2 < 4; ++mt2) {
        int rbase = wm + mt2 * 16 + q * 4;
#pragma unroll
        for (int i = 0; i < 4; ++i) {
            int r = rbase + i;
            if (r < mValid) {
                int tok = permS[r];
                float* orow = out + (size_t)tok * OUT_F + nt * 128;
#pragma unroll
                for (int nt2 = 0; nt2 < 4; ++nt2) {
                    int col = wn + nt2 * 16 + m;
                    float v = acc[mt2][nt2][i] + biasS[col];
                    orow[col] = v > 0.f ? v : 0.f;
                }
            }
        }
    }
}

extern "C" void kernel_launch(void* const* d_in, const int* in_sizes, int n_in,
                              void* d_out, int out_size, void* d_ws, size_t ws_size,
                              hipStream_t stream) {
    const float* x    = (const float*)d_in[0];
    const int*   idxs = (const int*)d_in[1];
    const float* w    = (const float*)d_in[2];
    const float* b    = (const float*)d_in[3];
    float* out = (float*)d_out;

    // ws layout: wT u16[16M] (32 MB) | xg u16[80*32*4096] (20 MB) | perm | offs | tile_off
    u16* wT = (u16*)d_ws;
    u16* xg = wT + (size_t)N_MODELS * IN_F * OUT_F;
    int* perm     = (int*)(xg + (size_t)MAX_MT * 32 * 4096);
    int* offs     = perm + N_TOK;
    int* tile_off = offs + (N_MODELS + 1);

    setup_kernel<<<1, 256, 0, stream>>>(idxs, perm, offs, tile_off);
    prep_kernel<<<WBLOCKS + XBLOCKS, 256, 0, stream>>>(w, x, perm, offs, tile_off, wT, xg);
    gemm_kernel<<<dim3(8, MAX_MT), 256, 0, stream>>>(xg, wT, b, perm, offs, tile_off, out);
}

// Round 7
// 184.462 us; speedup vs baseline: 1.0325x; 1.0032x over previous
//
#include <hip/hip_runtime.h>
#include <hip/hip_bf16.h>
#include <stdint.h>

#define N_MODELS 16
#define IN_F 1024
#define OUT_F 1024
#define N_TOK 8192
#define MAX_MT 80          // max m-tiles: 64 full + up to 15 fragmentation

typedef unsigned short u16;
using us4   = __attribute__((ext_vector_type(4))) unsigned short;
using s16x8 = __attribute__((ext_vector_type(8))) short;
using f32x4 = __attribute__((ext_vector_type(4))) float;

__device__ __forceinline__ u16 f2bf(float f) {
    union { float f; uint32_t u; } v;
    v.f = f;
    uint32_t u = v.u;
    u += 0x7fffu + ((u >> 16) & 1u);   // RNE
    return (u16)(u >> 16);
}

__device__ __forceinline__ void gload16(const u16* g, u16* l) {
    // async global->LDS DMA, 16 B/lane; LDS dest = wave-uniform base + lane*16
    __builtin_amdgcn_global_load_lds(
        (const __attribute__((address_space(1))) void*)g,
        (__attribute__((address_space(3))) void*)l, 16, 0, 0);
}

// ---------------- kernel 1: setup — hist + scan + deterministic rank scatter ----------------
#define ROW 17   // LDS row stride (ints) for [256][16] tables -> conflict-free
__global__ __launch_bounds__(256)
void setup_kernel(const int* __restrict__ idxs,
                  int* __restrict__ perm,
                  int* __restrict__ offs,       // [17]
                  int* __restrict__ tile_off)   // [17]
{
    __shared__ int cnt[256 * ROW];
    __shared__ int offsS[N_MODELS + 1];
    int t = threadIdx.x;

#pragma unroll
    for (int e = 0; e < N_MODELS; ++e) cnt[t * ROW + e] = 0;
    __syncthreads();

    int base = t * 32;
#pragma unroll
    for (int i = 0; i < 32; ++i) cnt[t * ROW + idxs[base + i]] += 1;
    __syncthreads();

#pragma unroll
    for (int s = 1; s < 256; s <<= 1) {
        int v[N_MODELS];
#pragma unroll
        for (int e = 0; e < N_MODELS; ++e)
            v[e] = (t >= s) ? cnt[(t - s) * ROW + e] : 0;
        __syncthreads();
#pragma unroll
        for (int e = 0; e < N_MODELS; ++e)
            cnt[t * ROW + e] += v[e];
        __syncthreads();
    }

    if (t == 0) {
        int o = 0, to = 0;
        for (int e = 0; e < N_MODELS; ++e) {
            int c = cnt[255 * ROW + e];
            offsS[e] = o;
            offs[e] = o; tile_off[e] = to;
            to += (c + 127) >> 7;
            o  += c;
        }
        offsS[N_MODELS] = o;
        offs[N_MODELS] = o; tile_off[N_MODELS] = to;
    }
    __syncthreads();

    int cur[N_MODELS];
#pragma unroll
    for (int e = 0; e < N_MODELS; ++e)
        cur[e] = offsS[e] + ((t > 0) ? cnt[(t - 1) * ROW + e] : 0);
    __syncthreads();
#pragma unroll
    for (int e = 0; e < N_MODELS; ++e) cnt[t * ROW + e] = cur[e];

#pragma unroll
    for (int i = 0; i < 32; ++i) {
        int tok = base + i;
        int e = idxs[tok];
        perm[cnt[t * ROW + e]++] = tok;
    }
}

// ---------------- kernel 2: prep — w-transpose (small blocks, 8 loads in flight) + x-gather ----------------
// wT layout (u16): ((((e*8 + nt)*32 + kb)*4 + q)*128 + n)*8 + j
// xg layout (u16): mt*131072 + kb*4096 + q*1024 + r*8 + j
#define WBLOCKS (16 * 8 * 64)   // 8192 (e, nt, 16-k group) — 8 KB fp32 per block
#define XBLOCKS (MAX_MT * 8)    // 640  (mt, 128-k group)

__global__ __launch_bounds__(256)
void prep_kernel(const float* __restrict__ w, const float* __restrict__ x,
                 const int* __restrict__ perm, const int* __restrict__ offs,
                 const int* __restrict__ tile_off,
                 u16* __restrict__ wT, u16* __restrict__ xg)
{
    int t  = threadIdx.x;
    int bx = blockIdx.x;

    if (bx < WBLOCKS) {
        // ---- w fp32 [k][n] -> wT bf16 frag-major; exactly 8 independent column loads ----
        int e  = bx >> 9;            // 8 nt * 64 kg = 512 blocks per expert
        int nt = (bx >> 6) & 7;
        int kg = bx & 63;            // 16-k group
        int n    = t & 127;
        int half = t >> 7;           // 0..1 (k-octet within the 16-k group)
        const float* wp = w + (size_t)e * (IN_F * OUT_F) + (size_t)kg * 16 * OUT_F
                            + (size_t)half * 8 * OUT_F + nt * 128 + n;
        float r[8];
#pragma unroll
        for (int j = 0; j < 8; ++j) r[j] = wp[(size_t)j * OUT_F];
        s16x8 v;
#pragma unroll
        for (int j = 0; j < 8; ++j) v[j] = (short)f2bf(r[j]);
        // global octet index ko_g = kg*2 + half; dest offset = ko_g*1024 + n*8
        u16* ob = wT + ((size_t)(e * 8 + nt) * 32) * 4096 + ((size_t)(kg * 2 + half)) * 1024 + n * 8;
        *(s16x8*)ob = v;
    } else {
        // ---- x fp32 gathered by perm -> xg bf16 frag-major (LDS-staged coalesced stores) ----
        __shared__ u16 sh[4096];
        int bx2 = bx - WBLOCKS;
        int mt  = bx2 >> 3;
        int kg  = bx2 & 7;           // 128-k group
        int total = tile_off[N_MODELS];
        if (mt >= total) return;
        int e = 0;
        while (tile_off[e + 1] <= mt) ++e;
        int s0   = offs[e] + (mt - tile_off[e]) * 128;
        int sEnd = offs[e + 1];
        int r0   = t >> 3;
        int apos = t & 7;
        int toks[4];
#pragma unroll
        for (int i = 0; i < 4; ++i) {
            int r = r0 + i * 32;
            toks[i] = (s0 + r < sEnd) ? perm[s0 + r] : -1;
        }
        u16* outx = xg + (size_t)mt * 32 * 4096;
        for (int kb4 = 0; kb4 < 4; ++kb4) {
            int kb = kg * 4 + kb4;
#pragma unroll
            for (int i = 0; i < 4; ++i) {
                int r = r0 + i * 32;
                int k = kb * 32 + apos * 4;
                float4 v;
                if (toks[i] >= 0) v = *(const float4*)(x + (size_t)toks[i] * IN_F + k);
                else              v = make_float4(0.f, 0.f, 0.f, 0.f);
                us4 pk; pk.x = f2bf(v.x); pk.y = f2bf(v.y); pk.z = f2bf(v.z); pk.w = f2bf(v.w);
                *(us4*)(&sh[(apos >> 1) * 1024 + r * 8 + (apos & 1) * 4]) = pk;
            }
            __syncthreads();
#pragma unroll
            for (int i = 0; i < 2; ++i) {
                int c = t + i * 256;
                *(s16x8*)(outx + (size_t)kb * 4096 + c * 8) = *(const s16x8*)(&sh[c * 8]);
            }
            __syncthreads();
        }
    }
}

// ---------------- kernel 3: grouped GEMM + bias + relu (m97 structure, pure DMA) ----------------
__global__ __launch_bounds__(256)
void gemm_kernel(const u16* __restrict__ xg, const u16* __restrict__ wT,
                 const float* __restrict__ bias,
                 const int* __restrict__ perm, const int* __restrict__ offs,
                 const int* __restrict__ tile_off,
                 float* __restrict__ out)
{
    __shared__ u16 As[4096];
    __shared__ u16 Bs[4096];
    __shared__ int   permS[128];
    __shared__ float biasS[128];
    __shared__ int   toS[N_MODELS + 1];

    int t  = threadIdx.x;
    int bt = blockIdx.y;            // flat m-tile id
    int nt = blockIdx.x;            // n-tile id

    if (t <= N_MODELS) toS[t] = tile_off[t];
    __syncthreads();
    if (bt >= toS[N_MODELS]) return;   // uniform

    int e = 0;
    while (toS[e + 1] <= bt) ++e;
    int s0   = offs[e] + (bt - toS[e]) * 128;
    int sEnd = offs[e + 1];
    int mValid = sEnd - s0; if (mValid > 128) mValid = 128;

    if (t < 128) {
        permS[t] = (s0 + t < sEnd) ? perm[s0 + t] : 0;
        biasS[t] = bias[(size_t)e * OUT_F + nt * 128 + t];
    }

    const u16* atile = xg + (size_t)bt * 32 * 4096;
    const u16* btile = wT + ((size_t)(e * 8 + nt) * 32) * 4096;

    int lane = t & 63;
    int wv   = t >> 6;
    int wm   = (wv >> 1) * 64;
    int wn   = (wv & 1) * 64;
    int m    = lane & 15;
    int q    = lane >> 4;

    f32x4 acc[4][4];
#pragma unroll
    for (int i = 0; i < 4; ++i)
#pragma unroll
        for (int j = 0; j < 4; ++j)
            acc[i][j] = (f32x4){0.f, 0.f, 0.f, 0.f};

    int c = wv * 2;   // this wave's 1 KB chunk base (8 chunks per 8 KB tile)

    for (int kb = 0; kb < 32; ++kb) {
        const u16* ga = atile + kb * 4096;
        const u16* gb = btile + kb * 4096;
        gload16(ga + (c    ) * 512 + lane * 8, &As[(c    ) * 512]);
        gload16(ga + (c + 1) * 512 + lane * 8, &As[(c + 1) * 512]);
        gload16(gb + (c    ) * 512 + lane * 8, &Bs[(c    ) * 512]);
        gload16(gb + (c + 1) * 512 + lane * 8, &Bs[(c + 1) * 512]);
        __syncthreads();

        s16x8 af[4], bf[4];
#pragma unroll
        for (int mt2 = 0; mt2 < 4; ++mt2)
            af[mt2] = *(const s16x8*)(&As[q * 1024 + (wm + mt2 * 16 + m) * 8]);
#pragma unroll
        for (int nt2 = 0; nt2 < 4; ++nt2)
            bf[nt2] = *(const s16x8*)(&Bs[q * 1024 + (wn + nt2 * 16 + m) * 8]);
#pragma unroll
        for (int mt2 = 0; mt2 < 4; ++mt2)
#pragma unroll
            for (int nt2 = 0; nt2 < 4; ++nt2)
                acc[mt2][nt2] = __builtin_amdgcn_mfma_f32_16x16x32_bf16(
                    af[mt2], bf[nt2], acc[mt2][nt2], 0, 0, 0);
        __syncthreads();
    }

    // epilogue: bias + relu, scatter rows by perm
#pragma unroll
    for (int mt2 = 0; mt2 < 4; ++mt2) {
        int rbase = wm + mt2 * 16 + q * 4;
#pragma unroll
        for (int i = 0; i < 4; ++i) {
            int r = rbase + i;
            if (r < mValid) {
                int tok = permS[r];
                float* orow = out + (size_t)tok * OUT_F + nt * 128;
#pragma unroll
                for (int nt2 = 0; nt2 < 4; ++nt2) {
                    int col = wn + nt2 * 16 + m;
                    float v = acc[mt2][nt2][i] + biasS[col];
                    orow[col] = v > 0.f ? v : 0.f;
                }
            }
        }
    }
}

extern "C" void kernel_launch(void* const* d_in, const int* in_sizes, int n_in,
                              void* d_out, int out_size, void* d_ws, size_t ws_size,
                              hipStream_t stream) {
    const float* x    = (const float*)d_in[0];
    const int*   idxs = (const int*)d_in[1];
    const float* w    = (const float*)d_in[2];
    const float* b    = (const float*)d_in[3];
    float* out = (float*)d_out;

    // ws layout: wT u16[16M] (32 MB) | xg u16[80*32*4096] (20 MB) | perm | offs | tile_off
    u16* wT = (u16*)d_ws;
    u16* xg = wT + (size_t)N_MODELS * IN_F * OUT_F;
    int* perm     = (int*)(xg + (size_t)MAX_MT * 32 * 4096);
    int* offs     = perm + N_TOK;
    int* tile_off = offs + (N_MODELS + 1);

    setup_kernel<<<1, 256, 0, stream>>>(idxs, perm, offs, tile_off);
    prep_kernel<<<WBLOCKS + XBLOCKS, 256, 0, stream>>>(w, x, perm, offs, tile_off, wT, xg);
    gemm_kernel<<<dim3(8, MAX_MT), 256, 0, stream>>>(xg, wT, b, perm, offs, tile_off, out);
}

// Round 8
// 184.163 us; speedup vs baseline: 1.0342x; 1.0016x over previous
//
#include <hip/hip_runtime.h>
#include <hip/hip_bf16.h>
#include <stdint.h>

#define N_MODELS 16
#define IN_F 1024
#define OUT_F 1024
#define N_TOK 8192
#define MAX_MT 80          // max m-tiles: 64 full + up to 15 fragmentation

typedef unsigned short u16;
using us4   = __attribute__((ext_vector_type(4))) unsigned short;
using s16x8 = __attribute__((ext_vector_type(8))) short;
using f32x4 = __attribute__((ext_vector_type(4))) float;

__device__ __forceinline__ u16 f2bf(float f) {
    union { float f; uint32_t u; } v;
    v.f = f;
    uint32_t u = v.u;
    u += 0x7fffu + ((u >> 16) & 1u);   // RNE
    return (u16)(u >> 16);
}

__device__ __forceinline__ void gload16(const u16* g, u16* l) {
    // async global->LDS DMA, 16 B/lane; LDS dest = wave-uniform base + lane*16
    __builtin_amdgcn_global_load_lds(
        (const __attribute__((address_space(1))) void*)g,
        (__attribute__((address_space(3))) void*)l, 16, 0, 0);
}

// ---------------- kernel 1: setup — hist + scan + deterministic rank scatter ----------------
#define ROW 17   // LDS row stride (ints) for [256][16] tables -> conflict-free
__global__ __launch_bounds__(256)
void setup_kernel(const int* __restrict__ idxs,
                  int* __restrict__ perm,
                  int* __restrict__ offs,       // [17]
                  int* __restrict__ tile_off)   // [17]
{
    __shared__ int cnt[256 * ROW];
    __shared__ int offsS[N_MODELS + 1];
    int t = threadIdx.x;

#pragma unroll
    for (int e = 0; e < N_MODELS; ++e) cnt[t * ROW + e] = 0;
    __syncthreads();

    int base = t * 32;
#pragma unroll
    for (int i = 0; i < 32; ++i) cnt[t * ROW + idxs[base + i]] += 1;
    __syncthreads();

#pragma unroll
    for (int s = 1; s < 256; s <<= 1) {
        int v[N_MODELS];
#pragma unroll
        for (int e = 0; e < N_MODELS; ++e)
            v[e] = (t >= s) ? cnt[(t - s) * ROW + e] : 0;
        __syncthreads();
#pragma unroll
        for (int e = 0; e < N_MODELS; ++e)
            cnt[t * ROW + e] += v[e];
        __syncthreads();
    }

    if (t == 0) {
        int o = 0, to = 0;
        for (int e = 0; e < N_MODELS; ++e) {
            int c = cnt[255 * ROW + e];
            offsS[e] = o;
            offs[e] = o; tile_off[e] = to;
            to += (c + 127) >> 7;
            o  += c;
        }
        offsS[N_MODELS] = o;
        offs[N_MODELS] = o; tile_off[N_MODELS] = to;
    }
    __syncthreads();

    int cur[N_MODELS];
#pragma unroll
    for (int e = 0; e < N_MODELS; ++e)
        cur[e] = offsS[e] + ((t > 0) ? cnt[(t - 1) * ROW + e] : 0);
    __syncthreads();
#pragma unroll
    for (int e = 0; e < N_MODELS; ++e) cnt[t * ROW + e] = cur[e];

#pragma unroll
    for (int i = 0; i < 32; ++i) {
        int tok = base + i;
        int e = idxs[tok];
        perm[cnt[t * ROW + e]++] = tok;
    }
}

// ---------------- kernel 2: prep — LDS-transpose w-path (float4 both ways) + x-gather ----------------
// wT layout (u16): (e*8 + nt)*131072 + ko_g*1024 + n*8 + j    (ko_g: global k-octet 0..127)
// xg layout (u16): mt*131072 + kb*4096 + q*1024 + r*8 + j
#define WBLOCKS (16 * 8 * 16)   // 2048 (e, nt, 64-k group)
#define XBLOCKS (MAX_MT * 8)    // 640  (mt, 128-k group)

__global__ __launch_bounds__(256)
void prep_kernel(const float* __restrict__ w, const float* __restrict__ x,
                 const int* __restrict__ perm, const int* __restrict__ offs,
                 const int* __restrict__ tile_off,
                 u16* __restrict__ wT, u16* __restrict__ xg)
{
    __shared__ float shf[64 * 128];   // 32 KB; x-path reuses first 8 KB as u16
    int t  = threadIdx.x;
    int bx = blockIdx.x;

    if (bx < WBLOCKS) {
        // ---- w fp32 [k][n] -> LDS [k][128] fp32 (float4, conflict-free) -> bf16 frag-major ----
        int e  = bx >> 7;
        int nt = (bx >> 4) & 7;
        int kg = bx & 15;            // 64-k group
        const float* wp = w + (size_t)e * (IN_F * OUT_F) + (size_t)kg * 64 * OUT_F + nt * 128;

        int n4  = (t & 31) * 4;      // float4 column start
        int kr0 = t >> 5;            // 0..7
#pragma unroll
        for (int i = 0; i < 8; ++i) {
            int k = kr0 + i * 8;
            const float4 v = *(const float4*)(wp + (size_t)k * OUT_F + n4);
            *(float4*)(&shf[k * 128 + n4]) = v;    // lanes n-contiguous -> conflict-free
        }
        __syncthreads();

        int n    = t & 127;
        int oct0 = t >> 7;           // 0..1
        u16* ob = wT + ((size_t)(e * 8 + nt)) * 131072 + (size_t)kg * 8192 + n * 8;
#pragma unroll
        for (int i = 0; i < 4; ++i) {
            int ko = oct0 + i * 2;   // local k-octet 0..7
            float r[8];
#pragma unroll
            for (int j = 0; j < 8; ++j)
                r[j] = shf[(ko * 8 + j) * 128 + n];   // lanes n-contiguous -> free
            union { us4 s; uint32_t u[2]; } pk0, pk1;
            union { __hip_bfloat162 h; uint32_t u; } c0, c1, c2, c3;
            c0.h = __float22bfloat162_rn(make_float2(r[0], r[1]));
            c1.h = __float22bfloat162_rn(make_float2(r[2], r[3]));
            c2.h = __float22bfloat162_rn(make_float2(r[4], r[5]));
            c3.h = __float22bfloat162_rn(make_float2(r[6], r[7]));
            pk0.u[0] = c0.u; pk0.u[1] = c1.u;
            pk1.u[0] = c2.u; pk1.u[1] = c3.u;
            union { s16x8 v; us4 h[2]; } outv;
            outv.h[0] = pk0.s; outv.h[1] = pk1.s;
            *(s16x8*)(ob + (size_t)ko * 1024) = outv.v;   // 1 KB/wave contiguous
        }
    } else {
        // ---- x fp32 gathered by perm -> xg bf16 frag-major (LDS-staged coalesced stores) ----
        u16* sh = (u16*)shf;
        int bx2 = bx - WBLOCKS;
        int mt  = bx2 >> 3;
        int kg  = bx2 & 7;           // 128-k group
        int total = tile_off[N_MODELS];
        if (mt >= total) return;
        int e = 0;
        while (tile_off[e + 1] <= mt) ++e;
        int s0   = offs[e] + (mt - tile_off[e]) * 128;
        int sEnd = offs[e + 1];
        int r0   = t >> 3;
        int apos = t & 7;
        int toks[4];
#pragma unroll
        for (int i = 0; i < 4; ++i) {
            int r = r0 + i * 32;
            toks[i] = (s0 + r < sEnd) ? perm[s0 + r] : -1;
        }
        u16* outx = xg + (size_t)mt * 32 * 4096;
        for (int kb4 = 0; kb4 < 4; ++kb4) {
            int kb = kg * 4 + kb4;
#pragma unroll
            for (int i = 0; i < 4; ++i) {
                int r = r0 + i * 32;
                int k = kb * 32 + apos * 4;
                float4 v;
                if (toks[i] >= 0) v = *(const float4*)(x + (size_t)toks[i] * IN_F + k);
                else              v = make_float4(0.f, 0.f, 0.f, 0.f);
                us4 pk; pk.x = f2bf(v.x); pk.y = f2bf(v.y); pk.z = f2bf(v.z); pk.w = f2bf(v.w);
                *(us4*)(&sh[(apos >> 1) * 1024 + r * 8 + (apos & 1) * 4]) = pk;
            }
            __syncthreads();
#pragma unroll
            for (int i = 0; i < 2; ++i) {
                int c = t + i * 256;
                *(s16x8*)(outx + (size_t)kb * 4096 + c * 8) = *(const s16x8*)(&sh[c * 8]);
            }
            __syncthreads();
        }
    }
}

// ---------------- kernel 3: grouped GEMM + bias + relu (m97 structure, pure DMA) ----------------
__global__ __launch_bounds__(256)
void gemm_kernel(const u16* __restrict__ xg, const u16* __restrict__ wT,
                 const float* __restrict__ bias,
                 const int* __restrict__ perm, const int* __restrict__ offs,
                 const int* __restrict__ tile_off,
                 float* __restrict__ out)
{
    __shared__ u16 As[4096];
    __shared__ u16 Bs[4096];
    __shared__ int   permS[128];
    __shared__ float biasS[128];
    __shared__ int   toS[N_MODELS + 1];

    int t  = threadIdx.x;
    int bt = blockIdx.y;            // flat m-tile id
    int nt = blockIdx.x;            // n-tile id

    if (t <= N_MODELS) toS[t] = tile_off[t];
    __syncthreads();
    if (bt >= toS[N_MODELS]) return;   // uniform

    int e = 0;
    while (toS[e + 1] <= bt) ++e;
    int s0   = offs[e] + (bt - toS[e]) * 128;
    int sEnd = offs[e + 1];
    int mValid = sEnd - s0; if (mValid > 128) mValid = 128;

    if (t < 128) {
        permS[t] = (s0 + t < sEnd) ? perm[s0 + t] : 0;
        biasS[t] = bias[(size_t)e * OUT_F + nt * 128 + t];
    }

    const u16* atile = xg + (size_t)bt * 32 * 4096;
    const u16* btile = wT + ((size_t)(e * 8 + nt)) * 131072;

    int lane = t & 63;
    int wv   = t >> 6;
    int wm   = (wv >> 1) * 64;
    int wn   = (wv & 1) * 64;
    int m    = lane & 15;
    int q    = lane >> 4;

    f32x4 acc[4][4];
#pragma unroll
    for (int i = 0; i < 4; ++i)
#pragma unroll
        for (int j = 0; j < 4; ++j)
            acc[i][j] = (f32x4){0.f, 0.f, 0.f, 0.f};

    int c = wv * 2;   // this wave's 1 KB chunk base (8 chunks per 8 KB tile)

    for (int kb = 0; kb < 32; ++kb) {
        const u16* ga = atile + kb * 4096;
        const u16* gb = btile + kb * 4096;
        gload16(ga + (c    ) * 512 + lane * 8, &As[(c    ) * 512]);
        gload16(ga + (c + 1) * 512 + lane * 8, &As[(c + 1) * 512]);
        gload16(gb + (c    ) * 512 + lane * 8, &Bs[(c    ) * 512]);
        gload16(gb + (c + 1) * 512 + lane * 8, &Bs[(c + 1) * 512]);
        __syncthreads();

        s16x8 af[4], bf[4];
#pragma unroll
        for (int mt2 = 0; mt2 < 4; ++mt2)
            af[mt2] = *(const s16x8*)(&As[q * 1024 + (wm + mt2 * 16 + m) * 8]);
#pragma unroll
        for (int nt2 = 0; nt2 < 4; ++nt2)
            bf[nt2] = *(const s16x8*)(&Bs[q * 1024 + (wn + nt2 * 16 + m) * 8]);
#pragma unroll
        for (int mt2 = 0; mt2 < 4; ++mt2)
#pragma unroll
            for (int nt2 = 0; nt2 < 4; ++nt2)
                acc[mt2][nt2] = __builtin_amdgcn_mfma_f32_16x16x32_bf16(
                    af[mt2], bf[nt2], acc[mt2][nt2], 0, 0, 0);
        __syncthreads();
    }

    // epilogue: bias + relu, scatter rows by perm
#pragma unroll
    for (int mt2 = 0; mt2 < 4; ++mt2) {
        int rbase = wm + mt2 * 16 + q * 4;
#pragma unroll
        for (int i = 0; i < 4; ++i) {
            int r = rbase + i;
            if (r < mValid) {
                int tok = permS[r];
                float* orow = out + (size_t)tok * OUT_F + nt * 128;
#pragma unroll
                for (int nt2 = 0; nt2 < 4; ++nt2) {
                    int col = wn + nt2 * 16 + m;
                    float v = acc[mt2][nt2][i] + biasS[col];
                    orow[col] = v > 0.f ? v : 0.f;
                }
            }
        }
    }
}

extern "C" void kernel_launch(void* const* d_in, const int* in_sizes, int n_in,
                              void* d_out, int out_size, void* d_ws, size_t ws_size,
                              hipStream_t stream) {
    const float* x    = (const float*)d_in[0];
    const int*   idxs = (const int*)d_in[1];
    const float* w    = (const float*)d_in[2];
    const float* b    = (const float*)d_in[3];
    float* out = (float*)d_out;

    // ws layout: wT u16[16M] (32 MB) | xg u16[80*32*4096] (20 MB) | perm | offs | tile_off
    u16* wT = (u16*)d_ws;
    u16* xg = wT + (size_t)N_MODELS * IN_F * OUT_F;
    int* perm     = (int*)(xg + (size_t)MAX_MT * 32 * 4096);
    int* offs     = perm + N_TOK;
    int* tile_off = offs + (N_MODELS + 1);

    setup_kernel<<<1, 256, 0, stream>>>(idxs, perm, offs, tile_off);
    prep_kernel<<<WBLOCKS + XBLOCKS, 256, 0, stream>>>(w, x, perm, offs, tile_off, wT, xg);
    gemm_kernel<<<dim3(8, MAX_MT), 256, 0, stream>>>(xg, wT, b, perm, offs, tile_off, out);
}